// Round 1
// 421.163 us; speedup vs baseline: 1.0875x; 1.0875x over previous
//
#include <hip/hip_runtime.h>
#include <math.h>

typedef unsigned short u16;
typedef __bf16 bf16x8 __attribute__((ext_vector_type(8)));
typedef float floatx4 __attribute__((ext_vector_type(4)));

constexpr int N_TOK = 8192;
constexpr int DIM   = 1024;
constexpr int CAP   = 128;      // candidate slots per row
constexpr float DELTA = 48.0f;  // exp2-domain candidate window (~20 sigma)
// softmax in exp2 domain: s2 = dot * (1/sqrt(1024)) * log2(e)
constexpr float SC2 = 0.03125f * 1.4426950408889634f;

__device__ __forceinline__ u16 f2bf(float f) {
  unsigned u = __builtin_bit_cast(unsigned, f);
  unsigned r = u + 0x7fffu + ((u >> 16) & 1u);  // round-to-nearest-even
  return (u16)(r >> 16);
}
__device__ __forceinline__ float bf2f(u16 h) {
  unsigned u = ((unsigned)h) << 16;
  return __builtin_bit_cast(float, u);
}
__device__ __forceinline__ floatx4 mfma16(bf16x8 a, bf16x8 b, floatx4 c) {
  return __builtin_amdgcn_mfma_f32_16x16x32_bf16(a, b, c, 0, 0, 0);
}
// async global->LDS, 16B per lane; LDS side is wave-uniform base + lane*16.
__device__ __forceinline__ void gload_lds16(const void* g, void* l) {
  using GP = const unsigned __attribute__((address_space(1)))*;
  using LP = unsigned __attribute__((address_space(3)))*;
  __builtin_amdgcn_global_load_lds((GP)(uintptr_t)g, (LP)(uintptr_t)l, 16, 0, 0);
}

// ---------------- generic fp32 -> bf16 hi/lo split (linear) ---------------
__global__ __launch_bounds__(256, 4) void split_mat(const float* __restrict__ src,
                                                    u16* __restrict__ oh,
                                                    u16* __restrict__ ol) {
  const size_t base = ((size_t)blockIdx.x * 256 + threadIdx.x) * 8;
  uint4 hv, lv;
  unsigned* hp = (unsigned*)&hv; unsigned* lp = (unsigned*)&lv;
#pragma unroll
  for (int q = 0; q < 4; ++q) {
    float a = src[base + q * 2], b = src[base + q * 2 + 1];
    u16 h0 = f2bf(a); u16 l0 = f2bf(a - bf2f(h0));
    u16 h1 = f2bf(b); u16 l1 = f2bf(b - bf2f(h1));
    hp[q] = (unsigned)h0 | ((unsigned)h1 << 16);
    lp[q] = (unsigned)l0 | ((unsigned)l1 << 16);
  }
  *(uint4*)(oh + base) = hv;
  *(uint4*)(ol + base) = lv;
}

// ---------------- G-pass: GT[e][d] = sum_n Wk[e][n]*Wq[d][n] (split-3) ----
__global__ __launch_bounds__(256, 2) void gemm_g(const u16* __restrict__ Wkh,
                                                 const u16* __restrict__ Wkl,
                                                 const u16* __restrict__ Wqh,
                                                 const u16* __restrict__ Wql,
                                                 u16* __restrict__ GThi,
                                                 u16* __restrict__ GTlo) {
  __shared__ u16 T[4][64 * 32];  // Ahi, Alo, Bhi, Blo
  const int t = threadIdx.x, w = t >> 6, l = t & 63;
  const int l15 = l & 15, l4 = l >> 4;
  const int cb = blockIdx.x, rb = blockIdx.y;
  const int wm = w & 1, wn = w >> 1;
  const int sl = l4 ^ (l15 & 3);

  const u16* sbase;
  if (w == 0)      sbase = Wkh + (size_t)rb * 64 * DIM;
  else if (w == 1) sbase = Wkl + (size_t)rb * 64 * DIM;
  else if (w == 2) sbase = Wqh + (size_t)cb * 64 * DIM;
  else             sbase = Wql + (size_t)cb * 64 * DIM;
  const u16* mysrc = sbase + (size_t)(l >> 2) * DIM + (((l & 3) ^ ((l >> 2) & 3)) * 8);

  floatx4 acc[2][2] = {};

  for (int k0 = 0; k0 < DIM; k0 += 32) {
    __syncthreads();
#pragma unroll
    for (int n = 0; n < 4; ++n)
      gload_lds16(mysrc + (size_t)n * 16 * DIM + k0, &T[w][n * 512]);
    __syncthreads();
    bf16x8 aH[2], aL[2], bH[2], bL[2];
#pragma unroll
    for (int i = 0; i < 2; ++i) {
      int ar = wm * 32 + i * 16 + l15;
      aH[i] = *(const bf16x8*)&T[0][ar * 32 + sl * 8];
      aL[i] = *(const bf16x8*)&T[1][ar * 32 + sl * 8];
      int br = wn * 32 + i * 16 + l15;
      bH[i] = *(const bf16x8*)&T[2][br * 32 + sl * 8];
      bL[i] = *(const bf16x8*)&T[3][br * 32 + sl * 8];
    }
#pragma unroll
    for (int i = 0; i < 2; ++i)
#pragma unroll
      for (int j = 0; j < 2; ++j) {
        acc[i][j] = mfma16(aL[i], bH[j], acc[i][j]);
        acc[i][j] = mfma16(aH[i], bL[j], acc[i][j]);
        acc[i][j] = mfma16(aH[i], bH[j], acc[i][j]);
      }
  }

#pragma unroll
  for (int i = 0; i < 2; ++i)
#pragma unroll
    for (int r = 0; r < 4; ++r) {
      size_t E = (size_t)(rb * 64 + wm * 32 + i * 16 + l4 * 4 + r);
#pragma unroll
      for (int j = 0; j < 2; ++j) {
        float v = acc[i][j][r];
        u16 h = f2bf(v);
        u16 lo = f2bf(v - bf2f(h));
        size_t off = E * DIM + (cb * 64 + wn * 32 + j * 16 + l15);
        GThi[off] = h;
        GTlo[off] = lo;
      }
    }
}

// ---------------- Y = X @ G, split-3 MFMA, 128x128 tile, grid (8,64) ------
__global__ __launch_bounds__(256, 2) void gemm_y(const u16* __restrict__ Xhi,
                                                 const u16* __restrict__ Xlo,
                                                 const u16* __restrict__ GThi,
                                                 const u16* __restrict__ GTlo,
                                                 u16* __restrict__ Yhi,
                                                 u16* __restrict__ Ylo) {
  __shared__ u16 T[4][128 * 32];
  const int t = threadIdx.x, w = t >> 6, l = t & 63;
  const int l15 = l & 15, l4 = l >> 4;
  const int nb = blockIdx.x, rb = blockIdx.y;
  const int col0 = nb * 128;
  const int wm = w & 1, wn = w >> 1;
  const int sl = l4 ^ (l15 & 3);

  const u16* sbase;
  if (w == 0)      sbase = Xhi + (size_t)rb * 128 * DIM;
  else if (w == 1) sbase = Xlo + (size_t)rb * 128 * DIM;
  else if (w == 2) sbase = GThi + (size_t)col0 * DIM;
  else             sbase = GTlo + (size_t)col0 * DIM;
  const u16* mysrc = sbase + (size_t)(l >> 2) * DIM + (((l & 3) ^ ((l >> 2) & 3)) * 8);

  floatx4 acc[4][4] = {};

  for (int k0 = 0; k0 < DIM; k0 += 32) {
    __syncthreads();
#pragma unroll
    for (int n = 0; n < 8; ++n)
      gload_lds16(mysrc + (size_t)n * 16 * DIM + k0, &T[w][n * 512]);
    __syncthreads();
    bf16x8 aH[4], aL[4], bH[4], bL[4];
#pragma unroll
    for (int i = 0; i < 4; ++i) {
      int ar = wm * 64 + i * 16 + l15;
      aH[i] = *(const bf16x8*)&T[0][ar * 32 + sl * 8];
      aL[i] = *(const bf16x8*)&T[1][ar * 32 + sl * 8];
      int br = wn * 64 + i * 16 + l15;
      bH[i] = *(const bf16x8*)&T[2][br * 32 + sl * 8];
      bL[i] = *(const bf16x8*)&T[3][br * 32 + sl * 8];
    }
#pragma unroll
    for (int i = 0; i < 4; ++i)
#pragma unroll
      for (int j = 0; j < 4; ++j) {
        acc[i][j] = mfma16(aL[i], bH[j], acc[i][j]);
        acc[i][j] = mfma16(aH[i], bL[j], acc[i][j]);
        acc[i][j] = mfma16(aH[i], bH[j], acc[i][j]);
      }
  }

#pragma unroll
  for (int i = 0; i < 4; ++i)
#pragma unroll
    for (int r = 0; r < 4; ++r) {
      size_t R = (size_t)(rb * 128 + wm * 64 + i * 16 + l4 * 4 + r);
#pragma unroll
      for (int j = 0; j < 4; ++j) {
        float v = acc[i][j][r];
        u16 h = f2bf(v);
        u16 lo = f2bf(v - bf2f(h));
        size_t off = R * DIM + (col0 + wn * 64 + j * 16 + l15);
        Yhi[off] = h;
        Ylo[off] = lo;
      }
    }
}

// ---------------- Pass S (approx): logits = Yhi Xhi^T * SC2 --------------
// 256x256 tile, BK=64, 512 threads (8 waves, 2M x 4N), 8-phase schedule
// (T2 xor-swizzle + T3/T4 counted vmcnt + T5 setprio). Per K-tile:
//   p1: read A[mq0]+B[nq0]          -> mfma quad(0,0)
//   p2: read A[mq1]    (B cached)   -> mfma quad(1,0)
//   p3: read B[nq1]; stage A(t+2)   -> mfma quad(0,1)  (A regs cached)
//   p4: stage B(t+2)                -> mfma quad(1,1); vmcnt(8); barrier
// Dead-region proof: A-LDS last read at p2 (drained at p2 lgkmcnt(0), all
// waves past p2-end barrier before p3 issues A(t+2) into the same buffer);
// B-LDS last read at p3 -> B(t+2) issued at p4. vmcnt(8) keeps exactly the
// current tile's 8 prefetch loads in flight across the tile boundary.
__global__ __launch_bounds__(512, 2) void gemm_s(const u16* __restrict__ Yhi,
                                                 const u16* __restrict__ Xhi,
                                                 float* __restrict__ Mpart,
                                                 unsigned* __restrict__ cnt,
                                                 uint2* __restrict__ cand) {
  __shared__ u16 TS[2][4][8192];   // [buf][A0,A1,B0,B1][128 rows x 64 k] = 128 KiB
  __shared__ float Mw[4][256];
  const int t = threadIdx.x, w = t >> 6, l = t & 63;
  const int l15 = l & 15, l4 = l >> 4;
  const int cb = blockIdx.x, rb = blockIdx.y;
  const int wm = w >> 2, wn = w & 3;

  // --- staging source (per-thread). Inverse T2 swizzle applied on the
  // global side; LDS dest stays linear (rule #21 both-sides-or-neither).
  const int row_t = t >> 3;                 // 0..63 (row within chunk)
  const int k8 = (t & 7) ^ (row_t & 7);     // xor-swizzled k-chunk
  const u16* srcA[2]; const u16* srcB[2];
  srcA[0] = Yhi + (size_t)(rb * 256 +       row_t) * DIM + k8 * 8;
  srcA[1] = Yhi + (size_t)(rb * 256 + 128 + row_t) * DIM + k8 * 8;
  srcB[0] = Xhi + (size_t)(cb * 256 +       row_t) * DIM + k8 * 8;
  srcB[1] = Xhi + (size_t)(cb * 256 + 128 + row_t) * DIM + k8 * 8;

  constexpr int NT = DIM / 64;  // 16 K-tiles

  // --- prologue: stage tile 0 -> buf0, tile 1 -> buf1 (8 insts each)
#pragma unroll
  for (int tt = 0; tt < 2; ++tt)
#pragma unroll
    for (int reg = 0; reg < 4; ++reg) {
      const u16* s = (reg < 2) ? srcA[reg] : srcB[reg - 2];
#pragma unroll
      for (int c = 0; c < 2; ++c)
        gload_lds16(s + (size_t)c * 64 * DIM + tt * 64,
                    &TS[tt][reg][c * 4096 + w * 512]);
    }
  asm volatile("s_waitcnt vmcnt(8)" ::: "memory");  // tile0 landed; tile1 in flight
  __builtin_amdgcn_s_barrier();

  floatx4 acc[8][4] = {};

#pragma unroll 2
  for (int kt = 0; kt < NT; ++kt) {
    const int buf = kt & 1;
    const u16* Abase = &TS[buf][wm][0];
    const u16* Bbase = &TS[buf][2 + (wn >> 1)][(wn & 1) * 64 * 64];
    bf16x8 a0[4][2], a1[4][2], bfr[2][2];

    // ================= phase 1: A[mq=0] + B[nq=0]; quad (0,0) ============
#pragma unroll
    for (int i = 0; i < 4; ++i)
#pragma unroll
      for (int ks = 0; ks < 2; ++ks)
        a0[i][ks] = *(const bf16x8*)&Abase[(i * 16 + l15) * 64 +
                                           (((ks * 4 + l4) ^ (l15 & 7)) * 8)];
#pragma unroll
    for (int j = 0; j < 2; ++j)
#pragma unroll
      for (int ks = 0; ks < 2; ++ks)
        bfr[j][ks] = *(const bf16x8*)&Bbase[(j * 16 + l15) * 64 +
                                            (((ks * 4 + l4) ^ (l15 & 7)) * 8)];
    __builtin_amdgcn_s_barrier();
    asm volatile("s_waitcnt lgkmcnt(0)" ::: "memory");
    __builtin_amdgcn_sched_barrier(0);
    __builtin_amdgcn_s_setprio(1);
#pragma unroll
    for (int i = 0; i < 4; ++i)
#pragma unroll
      for (int j = 0; j < 2; ++j) {
        acc[i][j] = mfma16(a0[i][0], bfr[j][0], acc[i][j]);
        acc[i][j] = mfma16(a0[i][1], bfr[j][1], acc[i][j]);
      }
    __builtin_amdgcn_s_setprio(0);
    __builtin_amdgcn_s_barrier();

    // ================= phase 2: A[mq=1]; quad (1,0) ======================
#pragma unroll
    for (int i = 0; i < 4; ++i)
#pragma unroll
      for (int ks = 0; ks < 2; ++ks)
        a1[i][ks] = *(const bf16x8*)&Abase[(64 + i * 16 + l15) * 64 +
                                           (((ks * 4 + l4) ^ (l15 & 7)) * 8)];
    __builtin_amdgcn_s_barrier();
    asm volatile("s_waitcnt lgkmcnt(0)" ::: "memory");
    __builtin_amdgcn_sched_barrier(0);
    __builtin_amdgcn_s_setprio(1);
#pragma unroll
    for (int i = 0; i < 4; ++i)
#pragma unroll
      for (int j = 0; j < 2; ++j) {
        acc[4 + i][j] = mfma16(a1[i][0], bfr[j][0], acc[4 + i][j]);
        acc[4 + i][j] = mfma16(a1[i][1], bfr[j][1], acc[4 + i][j]);
      }
    __builtin_amdgcn_s_setprio(0);
    __builtin_amdgcn_s_barrier();

    // ====== phase 3: B[nq=1]; stage A(kt+2); quad (0,1) (a0 cached) ======
#pragma unroll
    for (int j = 0; j < 2; ++j)
#pragma unroll
      for (int ks = 0; ks < 2; ++ks)
        bfr[j][ks] = *(const bf16x8*)&Bbase[(32 + j * 16 + l15) * 64 +
                                            (((ks * 4 + l4) ^ (l15 & 7)) * 8)];
    if (kt + 2 < NT) {
#pragma unroll
      for (int reg = 0; reg < 2; ++reg)
#pragma unroll
        for (int c = 0; c < 2; ++c)
          gload_lds16(srcA[reg] + (size_t)c * 64 * DIM + (kt + 2) * 64,
                      &TS[buf][reg][c * 4096 + w * 512]);
    }
    __builtin_amdgcn_s_barrier();
    asm volatile("s_waitcnt lgkmcnt(0)" ::: "memory");
    __builtin_amdgcn_sched_barrier(0);
    __builtin_amdgcn_s_setprio(1);
#pragma unroll
    for (int i = 0; i < 4; ++i)
#pragma unroll
      for (int j = 0; j < 2; ++j) {
        acc[i][2 + j] = mfma16(a0[i][0], bfr[j][0], acc[i][2 + j]);
        acc[i][2 + j] = mfma16(a0[i][1], bfr[j][1], acc[i][2 + j]);
      }
    __builtin_amdgcn_s_setprio(0);
    __builtin_amdgcn_s_barrier();

    // ====== phase 4: stage B(kt+2); quad (1,1); counted vmcnt ============
    if (kt + 2 < NT) {
#pragma unroll
      for (int reg = 2; reg < 4; ++reg)
#pragma unroll
        for (int c = 0; c < 2; ++c)
          gload_lds16(srcB[reg - 2] + (size_t)c * 64 * DIM + (kt + 2) * 64,
                      &TS[buf][reg][c * 4096 + w * 512]);
    }
    __builtin_amdgcn_s_barrier();
    asm volatile("s_waitcnt lgkmcnt(0)" ::: "memory");
    __builtin_amdgcn_sched_barrier(0);
    __builtin_amdgcn_s_setprio(1);
#pragma unroll
    for (int i = 0; i < 4; ++i)
#pragma unroll
      for (int j = 0; j < 2; ++j) {
        acc[4 + i][2 + j] = mfma16(a1[i][0], bfr[j][0], acc[4 + i][2 + j]);
        acc[4 + i][2 + j] = mfma16(a1[i][1], bfr[j][1], acc[4 + i][2 + j]);
      }
    __builtin_amdgcn_s_setprio(0);
    if (kt < NT - 2) asm volatile("s_waitcnt vmcnt(8)" ::: "memory");
    else             asm volatile("s_waitcnt vmcnt(0)" ::: "memory");
    __builtin_amdgcn_s_barrier();
  }

  // ---- epilogue: scale, per-row block max, candidate append ----
#pragma unroll
  for (int im = 0; im < 8; ++im)
#pragma unroll
    for (int jn = 0; jn < 4; ++jn)
#pragma unroll
      for (int r = 0; r < 4; ++r) acc[im][jn][r] *= SC2;

#pragma unroll
  for (int im = 0; im < 8; ++im)
#pragma unroll
    for (int r = 0; r < 4; ++r) {
      float m = fmaxf(fmaxf(acc[im][0][r], acc[im][1][r]),
                      fmaxf(acc[im][2][r], acc[im][3][r]));
#pragma unroll
      for (int off = 1; off <= 8; off <<= 1) m = fmaxf(m, __shfl_xor(m, off, 64));
      if (l15 == 0) Mw[wn][wm * 128 + im * 16 + l4 * 4 + r] = m;
    }
  __syncthreads();
#pragma unroll
  for (int im = 0; im < 8; ++im)
#pragma unroll
    for (int r = 0; r < 4; ++r) {
      int lr = wm * 128 + im * 16 + l4 * 4 + r;
      float mb = fmaxf(fmaxf(Mw[0][lr], Mw[1][lr]), fmaxf(Mw[2][lr], Mw[3][lr]));
      size_t R = (size_t)(rb * 256 + lr);
#pragma unroll
      for (int jn = 0; jn < 4; ++jn) {
        float v = acc[im][jn][r];
        if (v > mb - DELTA) {  // rare
          unsigned idx = atomicAdd(&cnt[R], 1u);
          if (idx < (unsigned)CAP) {
            unsigned col = (unsigned)(cb * 256 + wn * 64 + jn * 16 + l15);
            cand[R * CAP + idx] = make_uint2(col, __builtin_bit_cast(unsigned, v));
          }
        }
      }
    }
  if (t < 256) {
    float mb = fmaxf(fmaxf(Mw[0][t], Mw[1][t]), fmaxf(Mw[2][t], Mw[3][t]));
    Mpart[(size_t)cb * N_TOK + rb * 256 + t] = mb;
  }
}

// ---------------- finalize: exact softmax over survivors -----------------
// One wave per q-row. gmax from Mpart (32 col-blocks now); survivors =
// cand > gmax - DELTA; exact logits via fp32 dot of (Yhi+Ylo)x(Xhi+Xlo);
// output sum w*X (fp32).
__global__ __launch_bounds__(256, 4) void finalize(const uint2* __restrict__ cand,
                                                   const unsigned* __restrict__ cnt,
                                                   const float* __restrict__ Mpart,
                                                   const u16* __restrict__ Yhi,
                                                   const u16* __restrict__ Ylo,
                                                   const u16* __restrict__ Xhi,
                                                   const u16* __restrict__ Xlo,
                                                   const float* __restrict__ X,
                                                   float* __restrict__ Out) {
  const int t = threadIdx.x, w = t >> 6, l = t & 63;
  const int r = blockIdx.x * 4 + w;

  // global approx max over 32 block maxima (lanes 32-63 duplicate 0-31)
  float gm = Mpart[(size_t)(l & 31) * N_TOK + r];
#pragma unroll
  for (int off = 1; off <= 16; off <<= 1) gm = fmaxf(gm, __shfl_xor(gm, off, 64));

  int n = (int)cnt[r];
  if (n > CAP) n = CAP;
  const uint2* cr = cand + (size_t)r * CAP;

  // lane l examines slots l and l+64
  unsigned ccol[2];
  float aval[2];
#pragma unroll
  for (int s = 0; s < 2; ++s) {
    int idx = l + s * 64;
    ccol[s] = 0; aval[s] = -1e30f;
    if (idx < n) {
      uint2 e = cr[idx];
      ccol[s] = e.x;
      aval[s] = __builtin_bit_cast(float, e.y);
    }
  }

  // preload this row's Y (hi+lo) slice: lane covers d = l*16..l*16+15
  float yv[16];
  {
    const u16* yh = Yhi + (size_t)r * DIM + l * 16;
    const u16* yl = Ylo + (size_t)r * DIM + l * 16;
#pragma unroll
    for (int q = 0; q < 16; ++q) yv[q] = bf2f(yh[q]) + bf2f(yl[q]);
  }

  float sv_logit[8];
  int sv_col[8];
  int k = 0;
#pragma unroll
  for (int s = 0; s < 2; ++s) {
    unsigned long long mm = __ballot(aval[s] > gm - DELTA);
    while (mm && k < 8) {
      int li = (int)__ffsll(mm) - 1;
      mm &= mm - 1;
      int col = __shfl((int)ccol[s], li);
      const u16* xh = Xhi + (size_t)col * DIM + l * 16;
      const u16* xl = Xlo + (size_t)col * DIM + l * 16;
      float p = 0.f;
#pragma unroll
      for (int q = 0; q < 16; ++q) p = fmaf(yv[q], bf2f(xh[q]) + bf2f(xl[q]), p);
#pragma unroll
      for (int off = 1; off <= 32; off <<= 1) p += __shfl_xor(p, off, 64);
      sv_logit[k] = p * SC2;
      sv_col[k] = col;
      ++k;
    }
  }

  float m = -1e30f;
  for (int i = 0; i < k; ++i) m = fmaxf(m, sv_logit[i]);
  float wgt[8];
  float lsum = 0.f;
  for (int i = 0; i < k; ++i) {
    wgt[i] = __builtin_amdgcn_exp2f(sv_logit[i] - m);
    lsum += wgt[i];
  }
  const float inv = 1.0f / lsum;

  // output: lane covers cols l*16 .. l*16+15
  float4 o[4] = {};
  for (int i = 0; i < k; ++i) {
    const float wi = wgt[i] * inv;
    const float* xr = X + (size_t)sv_col[i] * DIM + l * 16;
#pragma unroll
    for (int c = 0; c < 4; ++c) {
      float4 xv = *(const float4*)(xr + c * 4);
      o[c].x = fmaf(wi, xv.x, o[c].x);
      o[c].y = fmaf(wi, xv.y, o[c].y);
      o[c].z = fmaf(wi, xv.z, o[c].z);
      o[c].w = fmaf(wi, xv.w, o[c].w);
    }
  }
  float* orow = Out + (size_t)r * DIM + l * 16;
#pragma unroll
  for (int c = 0; c < 4; ++c) *(float4*)(orow + c * 4) = o[c];
}

extern "C" void kernel_launch(void* const* d_in, const int* in_sizes, int n_in,
                              void* d_out, int out_size, void* d_ws, size_t ws_size,
                              hipStream_t stream) {
  const float* Wq = (const float*)d_in[0];
  const float* Wk = (const float*)d_in[1];
  const float* X  = (const float*)d_in[2];
  float* Out = (float*)d_out;

  constexpr size_t MAT = (size_t)N_TOK * DIM;   // 8 Mi elems
  constexpr size_t WMAT = (size_t)DIM * DIM;    // 1 Mi elems
  u16* Yhi = (u16*)d_ws;
  u16* Ylo = Yhi + MAT;
  u16* Xhi = Ylo + MAT;
  u16* Xlo = Xhi + MAT;
  u16* Wqh = Xlo + MAT;
  u16* Wql = Wqh + WMAT;
  u16* Wkh = Wql + WMAT;
  u16* Wkl = Wkh + WMAT;
  u16* GThi = Wkl + WMAT;
  u16* GTlo = GThi + WMAT;
  float* Mpart = (float*)(GTlo + WMAT);  // [32][8192] used (64 allocated)
  unsigned* cnt = (unsigned*)(Mpart + (size_t)64 * N_TOK);  // 32 KB
  uint2* cand = (uint2*)(cnt + N_TOK);   // [8192][CAP] uint2 = 8 MB

  split_mat<<<dim3(MAT / 2048), 256, 0, stream>>>(X, Xhi, Xlo);
  split_mat<<<dim3(WMAT / 2048), 256, 0, stream>>>(Wq, Wqh, Wql);
  split_mat<<<dim3(WMAT / 2048), 256, 0, stream>>>(Wk, Wkh, Wkl);
  hipMemsetAsync(cnt, 0, N_TOK * sizeof(unsigned), stream);
  gemm_g<<<dim3(16, 16), 256, 0, stream>>>(Wkh, Wkl, Wqh, Wql, GThi, GTlo);
  gemm_y<<<dim3(8, 64), 256, 0, stream>>>(Xhi, Xlo, GThi, GTlo, Yhi, Ylo);
  gemm_s<<<dim3(32, 32), 512, 0, stream>>>(Yhi, Xhi, Mpart, cnt, cand);
  finalize<<<dim3(N_TOK / 4), 256, 0, stream>>>(cand, cnt, Mpart, Yhi, Ylo,
                                                Xhi, Xlo, X, Out);
}